// Round 12
// baseline (51.598 us; speedup 1.0000x reference)
//
#include <hip/hip_runtime.h>
#include <math.h>

#define B_    16
#define N_    6
#define P_    70000
#define H_    112
#define W_    200
#define HW_   (H_ * W_)
#define BSN_  (B_ * N_)
#define HALF_ 56
#define CELLS_ (HALF_ * W_)            // 11200 cells, 44.8 KB LDS

// ---- K1 geometry: 288 blocks = (b, chunk), 512 thr x 8 iters = 4096 pts ----
#define AT_     512
#define AIT     8
#define ACHUNK  (AT_ * AIT)            // 4096
#define ACHUNKS 18                     // ceil(70000/4096)
#define NBLK    (B_ * ACHUNKS)         // 288
#define CAP     (ACHUNK * N_)          // 24576 = absolute max entries/block

// ws layout: gcorner[NBLK][24] | counts[NBLK] | pad | entries[NBLK][CAP] uint2
#define WS_GC_OFF   0
#define WS_CNT_OFF  (NBLK * 24 * 4)                   // 27648
#define WS_ENT_OFF  32768
#define WS_NEED     (WS_ENT_OFF + (size_t)NBLK * CAP * 8)   // ~56.7 MB

// ---------- shared math helpers (identical codegen everywhere) ----------

__device__ __forceinline__ float rdot4(float r0, float r1, float r2, float r3,
                                       float x, float y, float z) {
    float s = r0 * x;
    s = fmaf(r1, y, s);
    s = fmaf(r2, z, s);
    return s + r3;
}

// 4x4 inverse via adjugate (matches jnp.linalg.inv bit-for-bit here — absmax
// 0.0 through rounds 1-11)
__device__ __forceinline__ void inv4(const float* m, float* o) {
    float inv[16];
    inv[0]  =  m[5]*m[10]*m[15] - m[5]*m[11]*m[14] - m[9]*m[6]*m[15] + m[9]*m[7]*m[14] + m[13]*m[6]*m[11] - m[13]*m[7]*m[10];
    inv[4]  = -m[4]*m[10]*m[15] + m[4]*m[11]*m[14] + m[8]*m[6]*m[15] - m[8]*m[7]*m[14] - m[12]*m[6]*m[11] + m[12]*m[7]*m[10];
    inv[8]  =  m[4]*m[9]*m[15]  - m[4]*m[11]*m[13] - m[8]*m[5]*m[15] + m[8]*m[7]*m[13] + m[12]*m[5]*m[11] - m[12]*m[7]*m[9];
    inv[12] = -m[4]*m[9]*m[14]  + m[4]*m[10]*m[13] + m[8]*m[5]*m[14] - m[8]*m[6]*m[13] - m[12]*m[5]*m[10] + m[12]*m[6]*m[9];
    inv[1]  = -m[1]*m[10]*m[15] + m[1]*m[11]*m[14] + m[9]*m[2]*m[15] - m[9]*m[3]*m[14] - m[13]*m[2]*m[11] + m[13]*m[3]*m[10];
    inv[5]  =  m[0]*m[10]*m[15] - m[0]*m[11]*m[14] - m[8]*m[2]*m[15] + m[8]*m[3]*m[14] + m[12]*m[2]*m[11] - m[12]*m[3]*m[10];
    inv[9]  = -m[0]*m[9]*m[15]  + m[0]*m[11]*m[13] + m[8]*m[1]*m[15] - m[8]*m[3]*m[13] - m[12]*m[1]*m[11] + m[12]*m[3]*m[9];
    inv[13] =  m[0]*m[9]*m[14]  - m[0]*m[10]*m[13] - m[8]*m[1]*m[14] + m[8]*m[2]*m[13] + m[12]*m[1]*m[10] - m[12]*m[2]*m[9];
    inv[2]  =  m[1]*m[6]*m[15]  - m[1]*m[7]*m[14]  - m[5]*m[2]*m[15] + m[5]*m[3]*m[14] + m[13]*m[2]*m[7]  - m[13]*m[3]*m[6];
    inv[6]  = -m[0]*m[6]*m[15]  + m[0]*m[7]*m[14]  + m[4]*m[2]*m[15] - m[4]*m[3]*m[14] - m[12]*m[2]*m[7]  + m[12]*m[3]*m[6];
    inv[10] =  m[0]*m[5]*m[15]  - m[0]*m[7]*m[13]  - m[4]*m[1]*m[15] + m[4]*m[3]*m[13] + m[12]*m[1]*m[7]  - m[12]*m[3]*m[5];
    inv[14] = -m[0]*m[5]*m[14]  + m[0]*m[6]*m[13]  + m[4]*m[1]*m[14] - m[4]*m[2]*m[13] - m[12]*m[1]*m[6]  + m[12]*m[2]*m[5];
    inv[3]  = -m[1]*m[6]*m[11]  + m[1]*m[7]*m[10]  + m[5]*m[2]*m[11] - m[5]*m[3]*m[10] - m[9]*m[2]*m[7]   + m[9]*m[3]*m[6];
    inv[7]  =  m[0]*m[6]*m[11]  - m[0]*m[7]*m[10]  - m[4]*m[2]*m[11] + m[4]*m[3]*m[10] + m[8]*m[2]*m[7]   - m[8]*m[3]*m[6];
    inv[11] = -m[0]*m[5]*m[11]  + m[0]*m[7]*m[9]   + m[4]*m[1]*m[11] - m[4]*m[3]*m[9]  - m[8]*m[1]*m[7]   + m[8]*m[3]*m[5];
    inv[15] =  m[0]*m[5]*m[10]  - m[0]*m[6]*m[9]   - m[4]*m[1]*m[10] + m[4]*m[2]*m[9]  + m[8]*m[1]*m[6]   - m[8]*m[2]*m[5];
    float det = m[0]*inv[0] + m[1]*inv[4] + m[2]*inv[8] + m[3]*inv[12];
    float rdet = 1.0f / det;
    for (int i = 0; i < 16; ++i) o[i] = inv[i] * rdet;
}

// Per-camera: Einv (rigid inverse) and PFC = scale_intrinsics4(K) @ Einv.
__device__ __forceinline__ void cam_mats(const float* Ein, const float* Kin,
                                         float E2[4], float PFC[3][4]) {
    float Einv[4][4];
    for (int i = 0; i < 3; ++i)
        for (int j = 0; j < 3; ++j)
            Einv[i][j] = Ein[j * 4 + i];          // R^T
    for (int i = 0; i < 3; ++i) {                  // -(R^T t), asc-j fma
        float s = Ein[0 * 4 + i] * Ein[0 * 4 + 3];
        s = fmaf(Ein[1 * 4 + i], Ein[1 * 4 + 3], s);
        s = fmaf(Ein[2 * 4 + i], Ein[2 * 4 + 3], s);
        Einv[i][3] = -s;
    }
    Einv[3][0] = Ein[12]; Einv[3][1] = Ein[13];
    Einv[3][2] = Ein[14]; Einv[3][3] = Ein[15];

    float K4[4][4] = {};
    K4[0][0] = Kin[0] * 0.25f;  K4[0][2] = Kin[2] * 0.25f;
    K4[1][1] = Kin[4] * 0.25f;  K4[1][2] = Kin[5] * 0.25f;
    K4[2][2] = 1.0f;            K4[3][3] = 1.0f;

    for (int i = 0; i < 3; ++i)
        for (int j = 0; j < 4; ++j) {
            float s = K4[i][0] * Einv[0][j];
            s = fmaf(K4[i][1], Einv[1][j], s);
            s = fmaf(K4[i][2], Einv[2][j], s);
            s = fmaf(K4[i][3], Einv[3][j], s);
            PFC[i][j] = s;
        }
    for (int j = 0; j < 4; ++j) E2[j] = Einv[2][j];
}

// ---------- K1: one pass over points; 6 cams each; no divides in fast path
// Corner certainty via conservative screens on the EXACT px,py,denom:
//   px <= 0.99f*denom  =>  x_ = px/denom < 1      => xm == 0
//   px >= 201f *denom  =>  x_ > 200.99            => xm == 199
//   py <= 0.99f*denom  =>  ym == 0 ; py >= 113f*denom => ym == 111
// (denom > 0 always; fp32 div error << margins, so implication is exact.)
// Certain corners -> per-lane register max. Anything else -> rare path:
// exact reference divide/clip, entry appended to this block's ws segment.

__global__ __launch_bounds__(AT_) void k_scan(
        const float4* __restrict__ pc, const float* __restrict__ extr,
        const float* __restrict__ intr, const float* __restrict__ view,
        int* __restrict__ gcorner, int* __restrict__ counts,
        uint2* __restrict__ entries) {
    __shared__ float sM[84];           // 0..11 Vinv rows, 12.. 6x12 PFC
    __shared__ int   swc[8][24];       // per-wave corner maxima
    __shared__ int   scnt;

    const int b     = blockIdx.x;
    const int chunk = blockIdx.y;
    const int t     = threadIdx.x;
    const int lane  = t & 63;
    const int w     = t >> 6;

    if (t == 0) {                      // wave 0: Vinv + counter
        float Vi[16];
        inv4(&view[b * 16], Vi);
        for (int k = 0; k < 12; ++k) sM[k] = Vi[k];
        scnt = 0;
    } else if (t >= 64 && t < 64 + N_) {  // wave 1: 6 cameras
        int n = t - 64;
        float E2[4], PFC[3][4];
        cam_mats(&extr[(b * N_ + n) * 16], &intr[(b * N_ + n) * 9], E2, PFC);
        for (int i = 0; i < 3; ++i)
            for (int j = 0; j < 4; ++j) sM[12 + n * 12 + i * 4 + j] = PFC[i][j];
    }
    __syncthreads();

    // hoist all matrices to registers (amortized over AIT iterations)
    float V[12];
    #pragma unroll
    for (int k = 0; k < 12; ++k) V[k] = sM[k];
    float Pm[6][12];
    #pragma unroll
    for (int n = 0; n < 6; ++n)
        #pragma unroll
        for (int k = 0; k < 12; ++k) Pm[n][k] = sM[12 + n * 12 + k];

    int c[24];
    #pragma unroll
    for (int k = 0; k < 24; ++k) c[k] = -1;

    const int blk = b * ACHUNKS + chunk;
    uint2* ent = entries + (size_t)blk * CAP;
    const float4* pcb = pc + (size_t)b * P_;

    int p = chunk * ACHUNK + t;
    for (int it = 0; it < AIT; ++it, p += AT_) {
        bool valid = (p < P_);
        float4 pt = make_float4(0.f, 0.f, 0.f, 0.f);
        if (valid) pt = pcb[p];
        float lx = rdot4(V[0], V[1], V[2],  V[3],  pt.x, pt.y, pt.z);
        float ly = rdot4(V[4], V[5], V[6],  V[7],  pt.x, pt.y, pt.z);
        float lz = rdot4(V[8], V[9], V[10], V[11], pt.x, pt.y, pt.z);
        unsigned rfl = 0;
        #pragma unroll
        for (int n = 0; n < 6; ++n) {
            float px = rdot4(Pm[n][0], Pm[n][1], Pm[n][2],  Pm[n][3],  lx, ly, lz);
            float py = rdot4(Pm[n][4], Pm[n][5], Pm[n][6],  Pm[n][7],  lx, ly, lz);
            float pz = rdot4(Pm[n][8], Pm[n][9], Pm[n][10], Pm[n][11], lx, ly, lz);
            float denom = fmaxf(pz, 1e-6f);
            float tl = 0.99f * denom;
            float tx = 201.0f * denom;
            float ty = 113.0f * denom;
            bool x0 = (px <= tl), x1 = (px >= tx);
            bool y0 = (py <= tl), y1 = (py >= ty);
            if (valid) {
                if (x0 & y0) c[n * 4 + 0] = p;     // (0,0)
                if (x1 & y0) c[n * 4 + 1] = p;     // (0,199)
                if (x0 & y1) c[n * 4 + 2] = p;     // (111,0)
                if (x1 & y1) c[n * 4 + 3] = p;     // (111,199)
                if (!((x0 | x1) & (y0 | y1))) rfl |= (1u << n);
            }
        }
        if (__ballot(rfl != 0)) {                  // wave-uniform skip
            #pragma unroll
            for (int n = 0; n < 6; ++n) {
                if (rfl & (1u << n)) {
                    float px = rdot4(Pm[n][0], Pm[n][1], Pm[n][2],  Pm[n][3],  lx, ly, lz);
                    float py = rdot4(Pm[n][4], Pm[n][5], Pm[n][6],  Pm[n][7],  lx, ly, lz);
                    float pz = rdot4(Pm[n][8], Pm[n][9], Pm[n][10], Pm[n][11], lx, ly, lz);
                    float denom = fmaxf(pz, 1e-6f);
                    float x_ = px / denom;          // exact reference sequence
                    float y_ = py / denom;
                    int ym = (int)fminf(fmaxf(y_, 0.0f), (float)(H_ - 1));
                    int xm = (int)fminf(fmaxf(x_, 0.0f), (float)(W_ - 1));
                    int pos = atomicAdd(&scnt, 1);
                    ent[pos] = make_uint2(((unsigned)n << 15) |
                                          ((unsigned)ym << 8) | (unsigned)xm,
                                          (unsigned)p);
                }
            }
        }
    }

    // reduce corner maxima: lanes -> wave (shfl), waves -> block (LDS)
    #pragma unroll
    for (int k = 0; k < 24; ++k) {
        int v = c[k];
        for (int d = 32; d; d >>= 1) v = max(v, __shfl_xor(v, d));
        if (lane == 0) swc[w][k] = v;
    }
    __syncthreads();
    if (t < 24) {
        int v = -1;
        #pragma unroll
        for (int w2 = 0; w2 < 8; ++w2) v = max(v, swc[w2][t]);
        gcorner[blk * 24 + t] = v;
    }
    if (t == 32) counts[blk] = scnt;
}

// ---------- K2: corners + rare entries -> grid; finalize ----------

__global__ __launch_bounds__(1024) void k_fin(
        const float4* __restrict__ pc, const float* __restrict__ extr,
        const float* __restrict__ intr, const float* __restrict__ view,
        const int* __restrict__ gcorner, const int* __restrict__ counts,
        const uint2* __restrict__ entries,
        float* __restrict__ out, const int* __restrict__ bev_side_p) {
    __shared__ int   win[CELLS_];      // 44.8 KB
    __shared__ float sM[28];           // 0..11 Vinv, 12..23 PFC, 24..27 E2

    // XCD swizzle: batch b pinned to XCD b%8 (matches K1's blockIdx.x = b)
    const int i    = blockIdx.x;       // 0..191
    const int xcd  = i & 7;
    const int s    = i >> 3;
    const int b    = xcd + 8 * (s >= 12 ? 1 : 0);
    const int c12  = s % 12;
    const int cam  = c12 >> 1;
    const int half = c12 & 1;
    const int m    = b * N_ + cam;
    const int rlo  = half * HALF_;
    const int t    = threadIdx.x;

    if (t == 0) {
        float Vi[16];
        inv4(&view[b * 16], Vi);
        for (int k = 0; k < 12; ++k) sM[k] = Vi[k];
    } else if (t == 64) {
        float E2[4], PFC[3][4];
        cam_mats(&extr[m * 16], &intr[m * 9], E2, PFC);
        for (int ii = 0; ii < 3; ++ii)
            for (int jj = 0; jj < 4; ++jj) sM[12 + ii * 4 + jj] = PFC[ii][jj];
        for (int jj = 0; jj < 4; ++jj) sM[24 + jj] = E2[jj];
    }
    for (int k = t; k < CELLS_; k += 1024) win[k] = -1;
    __syncthreads();

    // corner inject: reduce this camera's 2 in-half corners over 18 blocks
    if (t < 2) {
        int cid = half * 2 + t;        // 0,1 (ym=0) or 2,3 (ym=111)
        int best = -1;
        for (int k = 0; k < ACHUNKS; ++k)
            best = max(best, gcorner[(b * ACHUNKS + k) * 24 + cam * 4 + cid]);
        if (best >= 0) {
            int cell = (half ? (HALF_ - 1) * W_ : 0) + (t ? (W_ - 1) : 0);
            atomicMax(&win[cell], best);
        }
    }

    // rare-entry scatter (few): scan this batch's 18 segments
    for (int k = 0; k < ACHUNKS; ++k) {
        const int cnt = counts[b * ACHUNKS + k];
        const uint2* ent = entries + (size_t)(b * ACHUNKS + k) * CAP;
        for (int e = t; e < cnt; e += 1024) {
            uint2 v = ent[e];
            int camE = (int)(v.x >> 15);
            int ym   = (int)((v.x >> 8) & 127u);
            int xm   = (int)(v.x & 255u);
            int rr   = ym - rlo;
            if (camE == cam && (unsigned)rr < (unsigned)HALF_)
                atomicMax(&win[rr * W_ + xm], (int)v.y);
        }
    }
    __syncthreads();

    // finalize (bit-exact path, proven rounds 1-11)
    const float bev_half = (float)bev_side_p[0] * 0.5f;   // 100.0
    const float clip_hi  = bev_half - 1.0f;               // 99.0
    const float4* pcb = pc + (size_t)b * P_;
    const int base0 = (m * 2) * HW_ + rlo * W_;
    for (int rr = t; rr < CELLS_; rr += 1024) {
        int wv = win[rr];
        float depth = 0.0f, iluv = 0.0f;
        if (wv >= 0) {
            float4 pt = pcb[wv];
            float lx = rdot4(sM[0],  sM[1],  sM[2],  sM[3],  pt.x, pt.y, pt.z);
            float ly = rdot4(sM[4],  sM[5],  sM[6],  sM[7],  pt.x, pt.y, pt.z);
            float lz = rdot4(sM[8],  sM[9],  sM[10], sM[11], pt.x, pt.y, pt.z);
            float z  = rdot4(sM[24], sM[25], sM[26], sM[27], lx, ly, lz);
            float px = rdot4(sM[12], sM[13], sM[14], sM[15], lx, ly, lz);
            float py = rdot4(sM[16], sM[17], sM[18], sM[19], lx, ly, lz);
            float pz = rdot4(sM[20], sM[21], sM[22], sM[23], lx, ly, lz);
            float denom = fmaxf(pz, 1e-6f);
            float x_ = px / denom;
            float y_ = py / denom;
            bool valid = (x_ > -0.5f) && (x_ < (float)W_ - 0.5f) &&
                         (y_ > -0.5f) && (y_ < (float)H_ - 0.5f) && (z > 0.0f);
            if (valid) {
                float d = fminf(fmaxf(pz, 0.0f), clip_hi);     // clip(normalizer,0,99)
                depth = d / bev_half;                           // /100
                float vi = fminf(fmaxf(pt.w, 0.0f), 255.0f);    // clip(ilu,0,255)
                iluv = log1pf(vi) / 5.545177444479562f;         // /log(256) as f32
            }
        }
        out[base0 + rr]       = depth;
        out[base0 + HW_ + rr] = iluv;
    }
}

// ---------- fallback (R8 single-kernel path, if ws too small) ----------

#define PMAIN 69632
#define PTAIL (P_ - PMAIN)

__global__ __launch_bounds__(1024, 4) void k_lidar_ilp(
        const float4* __restrict__ pc, const float* __restrict__ extr,
        const float* __restrict__ intr, const float* __restrict__ view,
        float* __restrict__ out, const int* __restrict__ bev_side_p) {
    __shared__ int   win[CELLS_];
    __shared__ float sM[28];

    const int i    = blockIdx.x;
    const int xcd  = i & 7;
    const int s    = i >> 3;
    const int b    = xcd + 8 * (s >= 12 ? 1 : 0);
    const int c12  = s % 12;
    const int m    = b * N_ + (c12 >> 1);
    const int rlo  = (c12 & 1) * HALF_;
    const int t    = threadIdx.x;

    if (t == 0) {
        float Vi[16];
        inv4(&view[b * 16], Vi);
        for (int k = 0; k < 12; ++k) sM[k] = Vi[k];
    } else if (t == 64) {
        float E2[4], PFC[3][4];
        cam_mats(&extr[m * 16], &intr[m * 9], E2, PFC);
        for (int ii = 0; ii < 3; ++ii)
            for (int jj = 0; jj < 4; ++jj) sM[12 + ii * 4 + jj] = PFC[ii][jj];
        for (int jj = 0; jj < 4; ++jj) sM[24 + jj] = E2[jj];
    }
    for (int k = t; k < CELLS_; k += 1024) win[k] = -1;
    __syncthreads();

    const float V0 = sM[0],  V1 = sM[1],  V2 = sM[2],  V3 = sM[3];
    const float V4 = sM[4],  V5 = sM[5],  V6 = sM[6],  V7 = sM[7];
    const float V8 = sM[8],  V9 = sM[9],  V10 = sM[10], V11 = sM[11];
    const float P00 = sM[12], P01 = sM[13], P02 = sM[14], P03 = sM[15];
    const float P10 = sM[16], P11 = sM[17], P12 = sM[18], P13 = sM[19];
    const float P20 = sM[20], P21 = sM[21], P22 = sM[22], P23 = sM[23];

    const float4* pcb = pc + (size_t)b * P_;
    int c0 = -1, c1 = -1, c2 = -1, c3 = -1;

#define PROC(PT, PIDX)                                                        \
    {                                                                         \
        float lx = rdot4(V0, V1, V2,  V3,  (PT).x, (PT).y, (PT).z);           \
        float ly = rdot4(V4, V5, V6,  V7,  (PT).x, (PT).y, (PT).z);           \
        float lz = rdot4(V8, V9, V10, V11, (PT).x, (PT).y, (PT).z);           \
        float px = rdot4(P00, P01, P02, P03, lx, ly, lz);                     \
        float py = rdot4(P10, P11, P12, P13, lx, ly, lz);                     \
        float pz = rdot4(P20, P21, P22, P23, lx, ly, lz);                     \
        float denom = fmaxf(pz, 1e-6f);                                       \
        float x_ = px / denom;                                                \
        float y_ = py / denom;                                                \
        int ym = (int)fminf(fmaxf(y_, 0.0f), (float)(H_ - 1));                \
        int xm = (int)fminf(fmaxf(x_, 0.0f), (float)(W_ - 1));                \
        bool is_c = (xm == 0 || xm == W_ - 1) && (ym == 0 || ym == H_ - 1);   \
        int code = ((ym != 0) << 1) | (xm != 0);                              \
        c0 = (is_c && code == 0) ? (PIDX) : c0;                               \
        c1 = (is_c && code == 1) ? (PIDX) : c1;                               \
        c2 = (is_c && code == 2) ? (PIDX) : c2;                               \
        c3 = (is_c && code == 3) ? (PIDX) : c3;                               \
        int rr = ym - rlo;                                                    \
        if (!is_c && (unsigned)rr < (unsigned)HALF_)                          \
            atomicMax(&win[rr * W_ + xm], (PIDX));                            \
    }

    for (int base = 0; base < PMAIN; base += 4 * 1024) {
        float4 q0 = pcb[base + t];
        float4 q1 = pcb[base + t + 1024];
        float4 q2 = pcb[base + t + 2 * 1024];
        float4 q3 = pcb[base + t + 3 * 1024];
        PROC(q0, base + t)
        PROC(q1, base + t + 1024)
        PROC(q2, base + t + 2 * 1024)
        PROC(q3, base + t + 3 * 1024)
    }
    if (t < PTAIL) {
        float4 q = pcb[PMAIN + t];
        PROC(q, PMAIN + t)
    }
#undef PROC

    for (int d = 32; d; d >>= 1) {
        c0 = max(c0, __shfl_xor(c0, d));
        c1 = max(c1, __shfl_xor(c1, d));
        c2 = max(c2, __shfl_xor(c2, d));
        c3 = max(c3, __shfl_xor(c3, d));
    }
    if ((t & 63) == 0) {
        if (rlo == 0) {
            if (c0 >= 0) atomicMax(&win[0],   c0);
            if (c1 >= 0) atomicMax(&win[199], c1);
        } else {
            if (c2 >= 0) atomicMax(&win[(H_ - 1 - rlo) * W_ + 0],   c2);
            if (c3 >= 0) atomicMax(&win[(H_ - 1 - rlo) * W_ + 199], c3);
        }
    }
    __syncthreads();

    const float bev_half = (float)bev_side_p[0] * 0.5f;
    const float clip_hi  = bev_half - 1.0f;
    const float E20 = sM[24], E21 = sM[25], E22 = sM[26], E23 = sM[27];
    const int base0 = (m * 2) * HW_ + rlo * W_;
    for (int r = t; r < CELLS_; r += 1024) {
        int w = win[r];
        float depth = 0.0f, iluv = 0.0f;
        if (w >= 0) {
            float4 pt = pcb[w];
            float lx = rdot4(V0, V1, V2,  V3,  pt.x, pt.y, pt.z);
            float ly = rdot4(V4, V5, V6,  V7,  pt.x, pt.y, pt.z);
            float lz = rdot4(V8, V9, V10, V11, pt.x, pt.y, pt.z);
            float z  = rdot4(E20, E21, E22, E23, lx, ly, lz);
            float px = rdot4(P00, P01, P02, P03, lx, ly, lz);
            float py = rdot4(P10, P11, P12, P13, lx, ly, lz);
            float pz = rdot4(P20, P21, P22, P23, lx, ly, lz);
            float denom = fmaxf(pz, 1e-6f);
            float x_ = px / denom;
            float y_ = py / denom;
            bool valid = (x_ > -0.5f) && (x_ < (float)W_ - 0.5f) &&
                         (y_ > -0.5f) && (y_ < (float)H_ - 0.5f) && (z > 0.0f);
            if (valid) {
                float d = fminf(fmaxf(pz, 0.0f), clip_hi);
                depth = d / bev_half;
                float vi = fminf(fmaxf(pt.w, 0.0f), 255.0f);
                iluv = log1pf(vi) / 5.545177444479562f;
            }
        }
        out[base0 + r]       = depth;
        out[base0 + HW_ + r] = iluv;
    }
}

// ---------- launch ----------

extern "C" void kernel_launch(void* const* d_in, const int* in_sizes, int n_in,
                              void* d_out, int out_size, void* d_ws, size_t ws_size,
                              hipStream_t stream) {
    const float4* pc  = (const float4*)d_in[0];
    const float* extr = (const float*)d_in[1];
    const float* intr = (const float*)d_in[2];
    const float* view = (const float*)d_in[3];
    const int*   bev  = (const int*)d_in[4];
    float* out = (float*)d_out;

    if (ws_size >= WS_NEED) {
        char* ws = (char*)d_ws;
        int*   gcorner = (int*)(ws + WS_GC_OFF);
        int*   counts  = (int*)(ws + WS_CNT_OFF);
        uint2* entries = (uint2*)(ws + WS_ENT_OFF);
        k_scan<<<dim3(B_, ACHUNKS), dim3(AT_), 0, stream>>>(
            pc, extr, intr, view, gcorner, counts, entries);
        k_fin<<<dim3(BSN_ * 2), dim3(1024), 0, stream>>>(
            pc, extr, intr, view, gcorner, counts, entries, out, bev);
    } else {
        k_lidar_ilp<<<dim3(BSN_ * 2), dim3(1024), 0, stream>>>(
            pc, extr, intr, view, out, bev);
    }
}